// Round 1
// baseline (276.963 us; speedup 1.0000x reference)
//
#include <hip/hip_runtime.h>
#include <math.h>

#define NN 1024
#define WW 128
#define DD 1024
#define FF (NN * WW + NN)  // 132096

// ---------------- Kernel A: per-column feature extractor ----------------
// f1 = relu(W1[n] @ x + b1[n]);  f2 = relu(W2[n] @ f1 + b2[n])
// writes feat[n*W + v] = f2[n,v]; thread 0 also writes feat[N*W + n] = hidden[n]
__global__ __launch_bounds__(256) void feat_kernel(
    const float* __restrict__ x, const float* __restrict__ hidden,
    const float* __restrict__ W1, const float* __restrict__ b1,
    const float* __restrict__ W2, const float* __restrict__ b2,
    float* __restrict__ feat)
{
    const int n    = blockIdx.x;
    const int tid  = threadIdx.x;
    const int lane = tid & 63;
    const int wave = tid >> 6;

    __shared__ float x_s[DD];
    __shared__ float f1_s[WW];

    // stage x into LDS (256 threads * float4 = 1024 floats)
    *reinterpret_cast<float4*>(x_s + tid * 4) =
        *reinterpret_cast<const float4*>(x + tid * 4);

    if (tid == 0) feat[NN * WW + n] = hidden[n];
    __syncthreads();

    // ---- f1: 4 waves x 32 rows, each row = 1024-long dot ----
    const float* W1n = W1 + (size_t)n * WW * DD;
    for (int r = wave * 32; r < wave * 32 + 32; ++r) {
        const float* row = W1n + (size_t)r * DD;
        float4 acc = {0.f, 0.f, 0.f, 0.f};
        #pragma unroll
        for (int it = 0; it < 4; ++it) {
            const float4 a  = *reinterpret_cast<const float4*>(row + it * 256 + lane * 4);
            const float4 xv = *reinterpret_cast<const float4*>(x_s + it * 256 + lane * 4);
            acc.x += a.x * xv.x; acc.y += a.y * xv.y;
            acc.z += a.z * xv.z; acc.w += a.w * xv.w;
        }
        float s = (acc.x + acc.y) + (acc.z + acc.w);
        #pragma unroll
        for (int m = 32; m > 0; m >>= 1) s += __shfl_xor(s, m, 64);
        if (lane == 0) {
            float v = s + b1[n * WW + r];
            f1_s[r] = v > 0.f ? v : 0.f;
        }
    }
    __syncthreads();

    // ---- f2: 4 waves x 32 rows, each row = 128-long dot ----
    const float* W2n = W2 + (size_t)n * WW * WW;
    for (int r = wave * 32; r < wave * 32 + 32; ++r) {
        const float2 a = *reinterpret_cast<const float2*>(W2n + (size_t)r * WW + lane * 2);
        const float2 f = *reinterpret_cast<const float2*>(f1_s + lane * 2);
        float s = a.x * f.x + a.y * f.y;
        #pragma unroll
        for (int m = 32; m > 0; m >>= 1) s += __shfl_xor(s, m, 64);
        if (lane == 0) {
            float v = s + b2[n * WW + r];
            feat[n * WW + r] = v > 0.f ? v : 0.f;
        }
    }
}

// ---------------- Kernel B: masked sparse dot + tanh ----------------
// i[n] = tanh(sum_f Wi[n,f]*mask[n,f]*feat[f] + bi[n]);  h = hidden + i
__global__ __launch_bounds__(256) void sparse_kernel(
    const float* __restrict__ Wi, const float* __restrict__ mask,
    const float* __restrict__ bi, const float* __restrict__ hidden,
    const float* __restrict__ feat, float* __restrict__ out)
{
    const int n   = blockIdx.x;
    const int tid = threadIdx.x;
    const float* mrow = mask + (size_t)n * FF;
    const float* wrow = Wi   + (size_t)n * FF;

    float acc = 0.f;
    // FF / (256 threads * 4 floats) = 129 exact iterations
    for (int it = 0; it < FF / 1024; ++it) {
        const int f = it * 1024 + tid * 4;
        const float4 m = *reinterpret_cast<const float4*>(mrow + f);
        if (m.x != 0.f) acc += wrow[f + 0] * m.x * feat[f + 0];
        if (m.y != 0.f) acc += wrow[f + 1] * m.y * feat[f + 1];
        if (m.z != 0.f) acc += wrow[f + 2] * m.z * feat[f + 2];
        if (m.w != 0.f) acc += wrow[f + 3] * m.w * feat[f + 3];
    }

    #pragma unroll
    for (int m = 32; m > 0; m >>= 1) acc += __shfl_xor(acc, m, 64);
    __shared__ float partial[4];
    if ((tid & 63) == 0) partial[tid >> 6] = acc;
    __syncthreads();
    if (tid == 0) {
        const float s  = (partial[0] + partial[1]) + (partial[2] + partial[3]);
        const float ii = tanhf(s + bi[n]);
        out[1 + n] = hidden[n] + ii;
    }
}

// ---------------- Kernel C: y = sum(pred * h) ----------------
__global__ __launch_bounds__(256) void pred_kernel(
    const float* __restrict__ pred, const float* __restrict__ h,
    float* __restrict__ out)
{
    const int tid = threadIdx.x;
    float acc = 0.f;
    for (int i = tid; i < NN; i += 256) acc += pred[i] * h[i];
    #pragma unroll
    for (int m = 32; m > 0; m >>= 1) acc += __shfl_xor(acc, m, 64);
    __shared__ float partial[4];
    if ((tid & 63) == 0) partial[tid >> 6] = acc;
    __syncthreads();
    if (tid == 0) out[0] = (partial[0] + partial[1]) + (partial[2] + partial[3]);
}

extern "C" void kernel_launch(void* const* d_in, const int* in_sizes, int n_in,
                              void* d_out, int out_size, void* d_ws, size_t ws_size,
                              hipStream_t stream) {
    const float* x      = (const float*)d_in[0];
    const float* hidden = (const float*)d_in[1];
    const float* W1     = (const float*)d_in[2];
    const float* b1     = (const float*)d_in[3];
    const float* W2     = (const float*)d_in[4];
    const float* b2     = (const float*)d_in[5];
    const float* Wi     = (const float*)d_in[6];
    const float* bi     = (const float*)d_in[7];
    const float* mask   = (const float*)d_in[8];
    const float* pred   = (const float*)d_in[9];

    float* out  = (float*)d_out;
    float* feat = (float*)d_ws;   // FF floats = 528384 bytes

    feat_kernel<<<NN, 256, 0, stream>>>(x, hidden, W1, b1, W2, b2, feat);
    sparse_kernel<<<NN, 256, 0, stream>>>(Wi, mask, bi, hidden, feat, out);
    pred_kernel<<<1, 256, 0, stream>>>(pred, out + 1, out);
}

// Round 3
// 265.194 us; speedup vs baseline: 1.0444x; 1.0444x over previous
//
#include <hip/hip_runtime.h>
#include <math.h>

#define NN 1024
#define WW 128
#define DD 1024
#define FF (NN * WW + NN)   // 132096
#define QF (FF / 4)         // 33024 floats per wave-quarter (129 * 256)
#define CAP 256             // list capacity per quarter (max expected ~190)

// ws layout: [feat: FF floats = 528384 B][counts: 4096 ints = 16384 B][lists: 1024*4*CAP float2 = 8 MB]
#define WS_COUNTS_OFF 528384
#define WS_LISTS_OFF  544768
#define WS_NEEDED     (WS_LISTS_OFF + (size_t)NN * 4 * CAP * 8)

typedef float f32x4 __attribute__((ext_vector_type(4)));
typedef float f32x2 __attribute__((ext_vector_type(2)));

__device__ __forceinline__ f32x4 nt4(const float* p) {
    return __builtin_nontemporal_load(reinterpret_cast<const f32x4*>(p));
}
__device__ __forceinline__ f32x2 nt2(const float* p) {
    return __builtin_nontemporal_load(reinterpret_cast<const f32x2*>(p));
}

// ---------------- Fused K1: feat extractor (even blocks) + mask compaction (odd blocks) ----------------
__global__ __launch_bounds__(256) void fused_kernel(
    const float* __restrict__ x, const float* __restrict__ hidden,
    const float* __restrict__ W1, const float* __restrict__ b1,
    const float* __restrict__ W2, const float* __restrict__ b2,
    const float* __restrict__ Wi, const float* __restrict__ mask,
    float* __restrict__ feat, int* __restrict__ counts, float2* __restrict__ lists)
{
    const int n    = blockIdx.x >> 1;
    const int tid  = threadIdx.x;
    const int lane = tid & 63;
    const int wave = tid >> 6;

    __shared__ float x_s[DD];
    __shared__ float f1_s[WW];

    if (blockIdx.x & 1) {
        // ---- scan path: row n, wave w owns quarter w of the mask row ----
        const float*  mrow = mask + (size_t)n * FF + wave * QF;
        const float*  wrow = Wi   + (size_t)n * FF + wave * QF;
        float2*       lrow = lists + ((size_t)n * 4 + wave) * CAP;
        const int     fb   = wave * QF;
        const uint64_t lt  = (1ull << lane) - 1;
        int base = 0;
        #pragma unroll 2
        for (int it = 0; it < QF / 256; ++it) {
            const int off = it * 256 + lane * 4;
            const f32x4 m = nt4(mrow + off);
            #pragma unroll
            for (int j = 0; j < 4; ++j) {
                const float mv = m[j];
                const bool  nz = (mv != 0.f);
                const unsigned long long b = __ballot(nz);
                if (nz) {
                    const int pos = base + __popcll(b & lt);
                    if (pos < CAP) {
                        float2 e;
                        e.x = __int_as_float(fb + off + j);
                        e.y = wrow[off + j] * mv;   // mv == 1.0 exactly
                        lrow[pos] = e;
                    }
                }
                base += (int)__popcll(b);
            }
        }
        if (lane == 0) counts[n * 4 + wave] = base < CAP ? base : CAP;
    } else {
        // ---- feat path: f1 = relu(W1[n]@x+b1); f2 = relu(W2[n]@f1+b2) -> feat ----
        *reinterpret_cast<float4*>(x_s + tid * 4) =
            *reinterpret_cast<const float4*>(x + tid * 4);
        if (tid == 0) feat[NN * WW + n] = hidden[n];
        __syncthreads();

        const float* W1n = W1 + (size_t)n * WW * DD;
        for (int r = wave * 32; r < wave * 32 + 32; r += 2) {
            const float* row0 = W1n + (size_t)r * DD;
            const float* row1 = row0 + DD;
            f32x4 a0 = {0.f, 0.f, 0.f, 0.f};
            f32x4 a1 = {0.f, 0.f, 0.f, 0.f};
            #pragma unroll
            for (int it = 0; it < 4; ++it) {
                const f32x4 w0 = nt4(row0 + it * 256 + lane * 4);
                const f32x4 w1 = nt4(row1 + it * 256 + lane * 4);
                const f32x4 xv = *reinterpret_cast<const f32x4*>(x_s + it * 256 + lane * 4);
                a0 += w0 * xv;
                a1 += w1 * xv;
            }
            float s0 = (a0[0] + a0[1]) + (a0[2] + a0[3]);
            float s1 = (a1[0] + a1[1]) + (a1[2] + a1[3]);
            #pragma unroll
            for (int m = 32; m > 0; m >>= 1) {
                s0 += __shfl_xor(s0, m, 64);
                s1 += __shfl_xor(s1, m, 64);
            }
            if (lane == 0) {
                const float v0 = s0 + b1[n * WW + r];
                const float v1 = s1 + b1[n * WW + r + 1];
                f1_s[r]     = v0 > 0.f ? v0 : 0.f;
                f1_s[r + 1] = v1 > 0.f ? v1 : 0.f;
            }
        }
        __syncthreads();

        const float* W2n = W2 + (size_t)n * WW * WW;
        for (int r = wave * 32; r < wave * 32 + 32; ++r) {
            const f32x2 a = nt2(W2n + (size_t)r * WW + lane * 2);
            const f32x2 f = *reinterpret_cast<const f32x2*>(f1_s + lane * 2);
            float s = a[0] * f[0] + a[1] * f[1];
            #pragma unroll
            for (int m = 32; m > 0; m >>= 1) s += __shfl_xor(s, m, 64);
            if (lane == 0) {
                const float v = s + b2[n * WW + r];
                feat[n * WW + r] = v > 0.f ? v : 0.f;
            }
        }
    }
}

// ---------------- K2: sparse dot from compacted lists + tanh + h ----------------
__global__ __launch_bounds__(256) void dot_kernel(
    const float2* __restrict__ lists, const int* __restrict__ counts,
    const float* __restrict__ bi, const float* __restrict__ hidden,
    const float* __restrict__ feat, float* __restrict__ out)
{
    const int n    = blockIdx.x;
    const int tid  = threadIdx.x;
    const int lane = tid & 63;
    const int wave = tid >> 6;
    const float2* lrow = lists + ((size_t)n * 4 + wave) * CAP;
    const int     cnt  = counts[n * 4 + wave];
    float acc = 0.f;
    for (int i = lane; i < cnt; i += 64) {
        const float2 e = lrow[i];
        acc += e.y * feat[__float_as_int(e.x)];
    }
    #pragma unroll
    for (int m = 32; m > 0; m >>= 1) acc += __shfl_xor(acc, m, 64);
    __shared__ float partial[4];
    if (lane == 0) partial[wave] = acc;
    __syncthreads();
    if (tid == 0) {
        const float s = (partial[0] + partial[1]) + (partial[2] + partial[3]);
        out[1 + n] = hidden[n] + tanhf(s + bi[n]);
    }
}

// ---------------- fallback (round-1 proven path) ----------------
__global__ __launch_bounds__(256) void feat_kernel(
    const float* __restrict__ x, const float* __restrict__ hidden,
    const float* __restrict__ W1, const float* __restrict__ b1,
    const float* __restrict__ W2, const float* __restrict__ b2,
    float* __restrict__ feat)
{
    const int n    = blockIdx.x;
    const int tid  = threadIdx.x;
    const int lane = tid & 63;
    const int wave = tid >> 6;
    __shared__ float x_s[DD];
    __shared__ float f1_s[WW];
    *reinterpret_cast<float4*>(x_s + tid * 4) =
        *reinterpret_cast<const float4*>(x + tid * 4);
    if (tid == 0) feat[NN * WW + n] = hidden[n];
    __syncthreads();
    const float* W1n = W1 + (size_t)n * WW * DD;
    for (int r = wave * 32; r < wave * 32 + 32; ++r) {
        const float* row = W1n + (size_t)r * DD;
        float4 acc = {0.f, 0.f, 0.f, 0.f};
        #pragma unroll
        for (int it = 0; it < 4; ++it) {
            const float4 a  = *reinterpret_cast<const float4*>(row + it * 256 + lane * 4);
            const float4 xv = *reinterpret_cast<const float4*>(x_s + it * 256 + lane * 4);
            acc.x += a.x * xv.x; acc.y += a.y * xv.y;
            acc.z += a.z * xv.z; acc.w += a.w * xv.w;
        }
        float s = (acc.x + acc.y) + (acc.z + acc.w);
        #pragma unroll
        for (int m = 32; m > 0; m >>= 1) s += __shfl_xor(s, m, 64);
        if (lane == 0) {
            float v = s + b1[n * WW + r];
            f1_s[r] = v > 0.f ? v : 0.f;
        }
    }
    __syncthreads();
    const float* W2n = W2 + (size_t)n * WW * WW;
    for (int r = wave * 32; r < wave * 32 + 32; ++r) {
        const float2 a = *reinterpret_cast<const float2*>(W2n + (size_t)r * WW + lane * 2);
        const float2 f = *reinterpret_cast<const float2*>(f1_s + lane * 2);
        float s = a.x * f.x + a.y * f.y;
        #pragma unroll
        for (int m = 32; m > 0; m >>= 1) s += __shfl_xor(s, m, 64);
        if (lane == 0) {
            float v = s + b2[n * WW + r];
            feat[n * WW + r] = v > 0.f ? v : 0.f;
        }
    }
}

__global__ __launch_bounds__(256) void sparse_kernel(
    const float* __restrict__ Wi, const float* __restrict__ mask,
    const float* __restrict__ bi, const float* __restrict__ hidden,
    const float* __restrict__ feat, float* __restrict__ out)
{
    const int n   = blockIdx.x;
    const int tid = threadIdx.x;
    const float* mrow = mask + (size_t)n * FF;
    const float* wrow = Wi   + (size_t)n * FF;
    float acc = 0.f;
    for (int it = 0; it < FF / 1024; ++it) {
        const int f = it * 1024 + tid * 4;
        const float4 m = *reinterpret_cast<const float4*>(mrow + f);
        if (m.x != 0.f) acc += wrow[f + 0] * m.x * feat[f + 0];
        if (m.y != 0.f) acc += wrow[f + 1] * m.y * feat[f + 1];
        if (m.z != 0.f) acc += wrow[f + 2] * m.z * feat[f + 2];
        if (m.w != 0.f) acc += wrow[f + 3] * m.w * feat[f + 3];
    }
    #pragma unroll
    for (int m = 32; m > 0; m >>= 1) acc += __shfl_xor(acc, m, 64);
    __shared__ float partial[4];
    if ((tid & 63) == 0) partial[tid >> 6] = acc;
    __syncthreads();
    if (tid == 0) {
        const float s  = (partial[0] + partial[1]) + (partial[2] + partial[3]);
        out[1 + n] = hidden[n] + tanhf(s + bi[n]);
    }
}

// ---------------- K3: y = sum(pred * h) ----------------
__global__ __launch_bounds__(256) void pred_kernel(
    const float* __restrict__ pred, const float* __restrict__ h,
    float* __restrict__ out)
{
    const int tid = threadIdx.x;
    float acc = 0.f;
    for (int i = tid; i < NN; i += 256) acc += pred[i] * h[i];
    #pragma unroll
    for (int m = 32; m > 0; m >>= 1) acc += __shfl_xor(acc, m, 64);
    __shared__ float partial[4];
    if ((tid & 63) == 0) partial[tid >> 6] = acc;
    __syncthreads();
    if (tid == 0) out[0] = (partial[0] + partial[1]) + (partial[2] + partial[3]);
}

extern "C" void kernel_launch(void* const* d_in, const int* in_sizes, int n_in,
                              void* d_out, int out_size, void* d_ws, size_t ws_size,
                              hipStream_t stream) {
    const float* x      = (const float*)d_in[0];
    const float* hidden = (const float*)d_in[1];
    const float* W1     = (const float*)d_in[2];
    const float* b1     = (const float*)d_in[3];
    const float* W2     = (const float*)d_in[4];
    const float* b2     = (const float*)d_in[5];
    const float* Wi     = (const float*)d_in[6];
    const float* bi     = (const float*)d_in[7];
    const float* mask   = (const float*)d_in[8];
    const float* pred   = (const float*)d_in[9];

    float* out    = (float*)d_out;
    float* feat   = (float*)d_ws;
    int*   counts = (int*)((char*)d_ws + WS_COUNTS_OFF);
    float2* lists = (float2*)((char*)d_ws + WS_LISTS_OFF);

    if (ws_size >= WS_NEEDED) {
        fused_kernel<<<2 * NN, 256, 0, stream>>>(x, hidden, W1, b1, W2, b2,
                                                 Wi, mask, feat, counts, lists);
        dot_kernel<<<NN, 256, 0, stream>>>(lists, counts, bi, hidden, feat, out);
    } else {
        feat_kernel<<<NN, 256, 0, stream>>>(x, hidden, W1, b1, W2, b2, feat);
        sparse_kernel<<<NN, 256, 0, stream>>>(Wi, mask, bi, hidden, feat, out);
    }
    pred_kernel<<<1, 256, 0, stream>>>(pred, out + 1, out);
}

// Round 4
// 258.103 us; speedup vs baseline: 1.0731x; 1.0275x over previous
//
#include <hip/hip_runtime.h>
#include <math.h>

#define NN 1024
#define WW 128
#define DD 1024
#define FF (NN * WW + NN)   // 132096
#define CAP 256

// ws layout: [feat: FF floats][counts: 4096 ints][lists: 1024*4*CAP float2]
#define WS_COUNTS_OFF 528384
#define WS_LISTS_OFF  544768
#define WS_NEEDED     (WS_LISTS_OFF + (size_t)NN * 4 * CAP * 8)

typedef float f32x4 __attribute__((ext_vector_type(4)));
typedef float f32x2 __attribute__((ext_vector_type(2)));
typedef const void __attribute__((address_space(1))) cgv;
typedef void __attribute__((address_space(3))) lsv;

#define WAIT_VM0 asm volatile("s_waitcnt vmcnt(0)" ::: "memory")
#define WAIT_VM1 asm volatile("s_waitcnt vmcnt(1)" ::: "memory")
#define WAIT_VM4 asm volatile("s_waitcnt vmcnt(4)" ::: "memory")
#define WAIT_LGKM0 asm volatile("s_waitcnt lgkmcnt(0)" ::: "memory")

__device__ __forceinline__ void gl_lds16(const float* g, float* l) {
    __builtin_amdgcn_global_load_lds((cgv*)g, (lsv*)l, 16, 0, 0);
}

__device__ __forceinline__ float wred(float s) {
    #pragma unroll
    for (int m = 32; m > 0; m >>= 1) s += __shfl_xor(s, m, 64);
    return s;
}

// ---------------- Kernel A: feat extractor, async-LDS pipelined ----------------
// 36 chunks of 4096 floats: c<32 -> W1 rows [4c,4c+4); c>=32 -> W2 quarter (c-32)
__global__ __launch_bounds__(256) void featA(
    const float* __restrict__ x, const float* __restrict__ hidden,
    const float* __restrict__ W1, const float* __restrict__ b1,
    const float* __restrict__ W2, const float* __restrict__ b2,
    float* __restrict__ feat)
{
    __shared__ float buf[2][4096];   // 2 x 16 KB
    __shared__ float x_s[DD];
    __shared__ float b1_s[WW], b2_s[WW], f1_s[WW];

    const int n = blockIdx.x, tid = threadIdx.x, lane = tid & 63, w = tid >> 6;
    const float* W1n = W1 + (size_t)n * WW * DD;
    const float* W2n = W2 + (size_t)n * WW * WW;

    // prologue staging (VGPR loads; drained by __syncthreads' vmcnt(0))
    *reinterpret_cast<float4*>(x_s + tid * 4) = *reinterpret_cast<const float4*>(x + tid * 4);
    if (tid < WW) b1_s[tid] = b1[n * WW + tid];
    else         b2_s[tid - WW] = b2[n * WW + (tid - WW)];
    if (tid == 0) feat[NN * WW + n] = hidden[n];
    __syncthreads();   // full drain: counted vmcnt below sees only staging loads

    // per-wave async stage of chunk c into buf[c&1] (wave w owns floats [w*1024, w*1024+1024))
    auto issueA = [&](int c) {
        const float* src = (c < 32) ? (W1n + c * 4096) : (W2n + (c - 32) * 4096);
        src += w * 1024 + lane * 4;
        float* dst = &buf[c & 1][w * 1024];   // wave-uniform base; HW scatters lane*16B
        #pragma unroll
        for (int k = 0; k < 4; ++k) gl_lds16(src + k * 256, dst + k * 256);
    };

    issueA(0);
    issueA(1);

    for (int c = 0; c < 36; ++c) {
        if (c == 35) { WAIT_VM0; } else { WAIT_VM4; }   // chunk c resident (in-order vmcnt)
        if (c == 32) { WAIT_LGKM0; __builtin_amdgcn_s_barrier(); }  // all f1 visible
        if (c < 32) {
            // one W1 row per wave: g = 4c + w
            const float* rp = &buf[c & 1][w * 1024];
            f32x4 a = {0.f, 0.f, 0.f, 0.f};
            #pragma unroll
            for (int k = 0; k < 4; ++k) {
                const f32x4 wv = *reinterpret_cast<const f32x4*>(rp + k * 256 + lane * 4);
                const f32x4 xv = *reinterpret_cast<const f32x4*>(x_s + k * 256 + lane * 4);
                a += wv * xv;
            }
            const float s = wred((a[0] + a[1]) + (a[2] + a[3]));
            if (lane == 0) {
                const int g = 4 * c + w;
                const float v = s + b1_s[g];
                f1_s[g] = v > 0.f ? v : 0.f;
            }
        } else {
            // 8 W2 rows per wave: local rows [8w, 8w+8) of this 32-row chunk
            const int cc = c - 32;
            #pragma unroll
            for (int j = 0; j < 8; ++j) {
                const int vl = 8 * w + j;
                const f32x2 av = *reinterpret_cast<const f32x2*>(&buf[c & 1][vl * 128 + lane * 2]);
                const f32x2 fv = *reinterpret_cast<const f32x2*>(&f1_s[lane * 2]);
                const float s = wred(av[0] * fv[0] + av[1] * fv[1]);
                if (lane == 0) {
                    const int g2 = cc * 32 + vl;
                    const float v = s + b2_s[g2];
                    feat[n * WW + g2] = v > 0.f ? v : 0.f;
                }
            }
        }
        if (c + 2 < 36) {
            WAIT_LGKM0;      // all ds_reads of chunk c retired before overwriting its buffer
            issueA(c + 2);
        }
    }
}

// ---------------- Kernel B: mask scan + compaction, async-LDS pipelined ----------------
// 33 chunks: c<32 -> 4096 floats; c==32 -> 1024 floats (hidden tail)
__global__ __launch_bounds__(256) void scanB(
    const float* __restrict__ Wi, const float* __restrict__ mask,
    int* __restrict__ counts, float2* __restrict__ lists)
{
    __shared__ float mbuf[2][4096];  // 2 x 16 KB

    const int n = blockIdx.x, tid = threadIdx.x, lane = tid & 63, w = tid >> 6;
    const float* mrow = mask + (size_t)n * FF;
    const float* wrow = Wi   + (size_t)n * FF;
    float2* lrow = lists + ((size_t)n * 4 + w) * CAP;
    const unsigned long long lt = (1ull << lane) - 1;
    int base = 0;

    auto issueB = [&](int c) {
        const int fb = (c < 32) ? c * 4096 + w * 1024 : 131072 + w * 256;
        const int nk = (c < 32) ? 4 : 1;
        const float* src = mrow + fb + lane * 4;
        float* dst = &mbuf[c & 1][w * 1024];
        for (int k = 0; k < nk; ++k) gl_lds16(src + k * 256, dst + k * 256);
    };

    issueB(0);
    issueB(1);

    for (int c = 0; c < 33; ++c) {
        if (c >= 32)      { WAIT_VM0; }
        else if (c == 31) { WAIT_VM1; }   // next chunk (32) has only 1 issue
        else              { WAIT_VM4; }
        const int nk = (c < 32) ? 4 : 1;
        const int fb = (c < 32) ? c * 4096 + w * 1024 : 131072 + w * 256;
        const float* seg = &mbuf[c & 1][w * 1024];
        for (int k = 0; k < nk; ++k) {
            const f32x4 m = *reinterpret_cast<const f32x4*>(seg + k * 256 + lane * 4);
            #pragma unroll
            for (int j = 0; j < 4; ++j) {
                const float mv = m[j];
                const bool nz = (mv != 0.f);
                const unsigned long long b = __ballot(nz);
                if (nz) {
                    const int pos = base + __popcll(b & lt);
                    if (pos < CAP) {
                        const int f = fb + k * 256 + lane * 4 + j;
                        float2 e;
                        e.x = __int_as_float(f);
                        e.y = wrow[f] * mv;   // mv == 1.0 exactly
                        lrow[pos] = e;
                    }
                }
                base += (int)__popcll(b);
            }
        }
        if (c + 2 < 33) {
            WAIT_LGKM0;
            issueB(c + 2);
        }
    }
    if (lane == 0) counts[n * 4 + w] = base < CAP ? base : CAP;
}

// ---------------- K2: sparse dot from compacted lists + tanh + h ----------------
__global__ __launch_bounds__(256) void dot_kernel(
    const float2* __restrict__ lists, const int* __restrict__ counts,
    const float* __restrict__ bi, const float* __restrict__ hidden,
    const float* __restrict__ feat, float* __restrict__ out)
{
    const int n = blockIdx.x, tid = threadIdx.x, lane = tid & 63, wave = tid >> 6;
    const float2* lrow = lists + ((size_t)n * 4 + wave) * CAP;
    const int cnt = counts[n * 4 + wave];
    float acc = 0.f;
    for (int i = lane; i < cnt; i += 64) {
        const float2 e = lrow[i];
        acc += e.y * feat[__float_as_int(e.x)];
    }
    acc = wred(acc);
    __shared__ float partial[4];
    if (lane == 0) partial[wave] = acc;
    __syncthreads();
    if (tid == 0) {
        const float s = (partial[0] + partial[1]) + (partial[2] + partial[3]);
        out[1 + n] = hidden[n] + tanhf(s + bi[n]);
    }
}

// ---------------- fallback (round-1 proven path) ----------------
__global__ __launch_bounds__(256) void feat_kernel(
    const float* __restrict__ x, const float* __restrict__ hidden,
    const float* __restrict__ W1, const float* __restrict__ b1,
    const float* __restrict__ W2, const float* __restrict__ b2,
    float* __restrict__ feat)
{
    const int n = blockIdx.x, tid = threadIdx.x, lane = tid & 63, wave = tid >> 6;
    __shared__ float x_s[DD];
    __shared__ float f1_s[WW];
    *reinterpret_cast<float4*>(x_s + tid * 4) = *reinterpret_cast<const float4*>(x + tid * 4);
    if (tid == 0) feat[NN * WW + n] = hidden[n];
    __syncthreads();
    const float* W1n = W1 + (size_t)n * WW * DD;
    for (int r = wave * 32; r < wave * 32 + 32; ++r) {
        const float* row = W1n + (size_t)r * DD;
        float4 acc = {0.f, 0.f, 0.f, 0.f};
        #pragma unroll
        for (int it = 0; it < 4; ++it) {
            const float4 a  = *reinterpret_cast<const float4*>(row + it * 256 + lane * 4);
            const float4 xv = *reinterpret_cast<const float4*>(x_s + it * 256 + lane * 4);
            acc.x += a.x * xv.x; acc.y += a.y * xv.y;
            acc.z += a.z * xv.z; acc.w += a.w * xv.w;
        }
        float s = wred((acc.x + acc.y) + (acc.z + acc.w));
        if (lane == 0) {
            float v = s + b1[n * WW + r];
            f1_s[r] = v > 0.f ? v : 0.f;
        }
    }
    __syncthreads();
    const float* W2n = W2 + (size_t)n * WW * WW;
    for (int r = wave * 32; r < wave * 32 + 32; ++r) {
        const float2 a = *reinterpret_cast<const float2*>(W2n + (size_t)r * WW + lane * 2);
        const float2 f = *reinterpret_cast<const float2*>(f1_s + lane * 2);
        float s = wred(a.x * f.x + a.y * f.y);
        if (lane == 0) {
            float v = s + b2[n * WW + r];
            feat[n * WW + r] = v > 0.f ? v : 0.f;
        }
    }
}

__global__ __launch_bounds__(256) void sparse_kernel(
    const float* __restrict__ Wi, const float* __restrict__ mask,
    const float* __restrict__ bi, const float* __restrict__ hidden,
    const float* __restrict__ feat, float* __restrict__ out)
{
    const int n = blockIdx.x, tid = threadIdx.x;
    const float* mrow = mask + (size_t)n * FF;
    const float* wrow = Wi   + (size_t)n * FF;
    float acc = 0.f;
    for (int it = 0; it < FF / 1024; ++it) {
        const int f = it * 1024 + tid * 4;
        const float4 m = *reinterpret_cast<const float4*>(mrow + f);
        if (m.x != 0.f) acc += wrow[f + 0] * m.x * feat[f + 0];
        if (m.y != 0.f) acc += wrow[f + 1] * m.y * feat[f + 1];
        if (m.z != 0.f) acc += wrow[f + 2] * m.z * feat[f + 2];
        if (m.w != 0.f) acc += wrow[f + 3] * m.w * feat[f + 3];
    }
    acc = wred(acc);
    __shared__ float partial[4];
    if ((tid & 63) == 0) partial[tid >> 6] = acc;
    __syncthreads();
    if (tid == 0) {
        const float s = (partial[0] + partial[1]) + (partial[2] + partial[3]);
        out[1 + n] = hidden[n] + tanhf(s + bi[n]);
    }
}

// ---------------- K3: y = sum(pred * h) ----------------
__global__ __launch_bounds__(256) void pred_kernel(
    const float* __restrict__ pred, const float* __restrict__ h,
    float* __restrict__ out)
{
    const int tid = threadIdx.x;
    float acc = 0.f;
    for (int i = tid; i < NN; i += 256) acc += pred[i] * h[i];
    acc = wred(acc);
    __shared__ float partial[4];
    if ((tid & 63) == 0) partial[tid >> 6] = acc;
    __syncthreads();
    if (tid == 0) out[0] = (partial[0] + partial[1]) + (partial[2] + partial[3]);
}

extern "C" void kernel_launch(void* const* d_in, const int* in_sizes, int n_in,
                              void* d_out, int out_size, void* d_ws, size_t ws_size,
                              hipStream_t stream) {
    const float* x      = (const float*)d_in[0];
    const float* hidden = (const float*)d_in[1];
    const float* W1     = (const float*)d_in[2];
    const float* b1     = (const float*)d_in[3];
    const float* W2     = (const float*)d_in[4];
    const float* b2     = (const float*)d_in[5];
    const float* Wi     = (const float*)d_in[6];
    const float* bi     = (const float*)d_in[7];
    const float* mask   = (const float*)d_in[8];
    const float* pred   = (const float*)d_in[9];

    float*  out    = (float*)d_out;
    float*  feat   = (float*)d_ws;
    int*    counts = (int*)((char*)d_ws + WS_COUNTS_OFF);
    float2* lists  = (float2*)((char*)d_ws + WS_LISTS_OFF);

    if (ws_size >= WS_NEEDED) {
        featA<<<NN, 256, 0, stream>>>(x, hidden, W1, b1, W2, b2, feat);
        scanB<<<NN, 256, 0, stream>>>(Wi, mask, counts, lists);
        dot_kernel<<<NN, 256, 0, stream>>>(lists, counts, bi, hidden, feat, out);
    } else {
        feat_kernel<<<NN, 256, 0, stream>>>(x, hidden, W1, b1, W2, b2, feat);
        sparse_kernel<<<NN, 256, 0, stream>>>(Wi, mask, bi, hidden, feat, out);
    }
    pred_kernel<<<1, 256, 0, stream>>>(pred, out + 1, out);
}

// Round 5
// 238.645 us; speedup vs baseline: 1.1606x; 1.0815x over previous
//
#include <hip/hip_runtime.h>
#include <math.h>

#define NN 1024
#define WW 128
#define DD 1024
#define FF (NN * WW + NN)     // 132096
#define NCHUNK 516            // 256-float wave-chunks per mask row (516*256 = 132096)
#define NWORD (NCHUNK * 4)    // 2064 u64 bitmap words per row

// ws layout: [feat: FF floats = 528384 B][bitmap: 1024*2064 u64 = 16908288 B]
#define WS_BM_OFF  528384
#define WS_NEEDED  (WS_BM_OFF + (size_t)NN * NWORD * 8)

typedef float f32x4 __attribute__((ext_vector_type(4)));
typedef float f32x2 __attribute__((ext_vector_type(2)));

__device__ __forceinline__ f32x4 nt4(const float* p) {
    return __builtin_nontemporal_load(reinterpret_cast<const f32x4*>(p));
}
__device__ __forceinline__ f32x2 nt2(const float* p) {
    return __builtin_nontemporal_load(reinterpret_cast<const f32x2*>(p));
}
__device__ __forceinline__ float wred(float s) {
    #pragma unroll
    for (int m = 32; m > 0; m >>= 1) s += __shfl_xor(s, m, 64);
    return s;
}

// ---------------- K1: per-column MLP (f1 -> f2 -> feat), pure-VGPR streams ----------------
__global__ __launch_bounds__(256) void colmlp(
    const float* __restrict__ x, const float* __restrict__ hidden,
    const float* __restrict__ W1, const float* __restrict__ b1,
    const float* __restrict__ W2, const float* __restrict__ b2,
    float* __restrict__ feat)
{
    __shared__ float f1_s[WW];
    const int n = blockIdx.x, tid = threadIdx.x, lane = tid & 63, w = tid >> 6;

    // x slice pinned in VGPRs: lane covers d = k*256 + lane*4 + {0..3}
    f32x4 xv0 = *reinterpret_cast<const f32x4*>(x +   0 + lane * 4);
    f32x4 xv1 = *reinterpret_cast<const f32x4*>(x + 256 + lane * 4);
    f32x4 xv2 = *reinterpret_cast<const f32x4*>(x + 512 + lane * 4);
    f32x4 xv3 = *reinterpret_cast<const f32x4*>(x + 768 + lane * 4);

    const float* W1n = W1 + (size_t)n * WW * DD;
    // phase 1: wave w owns rows [w*32, w*32+32), 4 groups of 8 fully-unrolled rows
    for (int g = 0; g < 4; ++g) {
        const float* rp = W1n + (size_t)(w * 32 + g * 8) * DD + lane * 4;
        float p[8];
        #pragma unroll
        for (int i = 0; i < 8; ++i) {
            const float* r = rp + (size_t)i * DD;
            f32x4 a = nt4(r) * xv0;
            a += nt4(r + 256) * xv1;
            a += nt4(r + 512) * xv2;
            a += nt4(r + 768) * xv3;
            p[i] = (a[0] + a[1]) + (a[2] + a[3]);
        }
        #pragma unroll
        for (int i = 0; i < 8; ++i) {
            const float s = wred(p[i]);
            if (lane == 0) {
                const int rr = w * 32 + g * 8 + i;
                const float v = s + b1[n * WW + rr];
                f1_s[rr] = v > 0.f ? v : 0.f;
            }
        }
    }
    __syncthreads();

    // phase 2: f2 = relu(W2@f1 + b2) -> feat. lane covers u = lane*2, lane*2+1
    const float* W2n = W2 + (size_t)n * WW * WW;
    const f32x2 f1v = *reinterpret_cast<const f32x2*>(&f1_s[lane * 2]);
    for (int g = 0; g < 4; ++g) {
        float p[8];
        #pragma unroll
        for (int i = 0; i < 8; ++i) {
            const int rr = w * 32 + g * 8 + i;
            const f32x2 a = nt2(W2n + (size_t)rr * WW + lane * 2);
            p[i] = a[0] * f1v[0] + a[1] * f1v[1];
        }
        #pragma unroll
        for (int i = 0; i < 8; ++i) {
            const float s = wred(p[i]);
            if (lane == 0) {
                const int rr = w * 32 + g * 8 + i;
                const float v = s + b2[n * WW + rr];
                feat[n * WW + rr] = v > 0.f ? v : 0.f;
            }
        }
    }
    if (tid == 0) feat[NN * WW + n] = hidden[n];
}

// ---------------- K2: mask -> bitmap, memcpy-shaped (no divergent mem ops) ----------------
__global__ __launch_bounds__(256) void maskscan(
    const float* __restrict__ mask, unsigned long long* __restrict__ bm)
{
    const int tid = threadIdx.x, lane = tid & 63, w = tid >> 6;
    const int wave_id = blockIdx.x * 4 + w;
    const int nwaves  = gridDim.x * 4;
    const int total   = NN * NCHUNK;   // 528384 wave-chunks of 256 floats
    #pragma unroll 2
    for (int c = wave_id; c < total; c += nwaves) {
        const f32x4 m = nt4(mask + (size_t)c * 256 + lane * 4);
        const unsigned long long b0 = __ballot(m[0] != 0.f);
        const unsigned long long b1 = __ballot(m[1] != 0.f);
        const unsigned long long b2 = __ballot(m[2] != 0.f);
        const unsigned long long b3 = __ballot(m[3] != 0.f);
        if (lane < 4) {
            const unsigned long long v = lane == 0 ? b0 : lane == 1 ? b1 : lane == 2 ? b2 : b3;
            bm[(size_t)c * 4 + lane] = v;
        }
    }
}

// ---------------- K3: bitmap-driven sparse dot + tanh + h ----------------
__global__ __launch_bounds__(256) void dotk(
    const unsigned long long* __restrict__ bm, const float* __restrict__ Wi,
    const float* __restrict__ feat, const float* __restrict__ bi,
    const float* __restrict__ hidden, float* __restrict__ out)
{
    const int n = blockIdx.x, tid = threadIdx.x;
    const unsigned long long* brow = bm + (size_t)n * NWORD;
    const float* wrow = Wi + (size_t)n * FF;
    float acc = 0.f;
    for (int wd = tid; wd < NWORD; wd += 256) {
        unsigned long long b = brow[wd];
        const int basef = (wd >> 2) * 256 + (wd & 3);
        while (b) {
            const int l = __builtin_ctzll(b);
            const int f = basef + l * 4;
            acc += wrow[f] * feat[f];   // mask value is exactly 1.0
            b &= b - 1;
        }
    }
    acc = wred(acc);
    __shared__ float partial[4];
    if ((tid & 63) == 0) partial[tid >> 6] = acc;
    __syncthreads();
    if (tid == 0) {
        const float s = (partial[0] + partial[1]) + (partial[2] + partial[3]);
        out[1 + n] = hidden[n] + tanhf(s + bi[n]);
    }
}

// ---------------- K4: y = sum(pred * h) ----------------
__global__ __launch_bounds__(256) void predk(
    const float* __restrict__ pred, const float* __restrict__ h,
    float* __restrict__ out)
{
    const int tid = threadIdx.x;
    float acc = 0.f;
    for (int i = tid; i < NN; i += 256) acc += pred[i] * h[i];
    acc = wred(acc);
    __shared__ float partial[4];
    if ((tid & 63) == 0) partial[tid >> 6] = acc;
    __syncthreads();
    if (tid == 0) out[0] = (partial[0] + partial[1]) + (partial[2] + partial[3]);
}

// ---------------- fallback (round-1 proven path, used if ws too small) ----------------
__global__ __launch_bounds__(256) void feat_kernel(
    const float* __restrict__ x, const float* __restrict__ hidden,
    const float* __restrict__ W1, const float* __restrict__ b1,
    const float* __restrict__ W2, const float* __restrict__ b2,
    float* __restrict__ feat)
{
    const int n = blockIdx.x, tid = threadIdx.x, lane = tid & 63, wave = tid >> 6;
    __shared__ float x_s[DD];
    __shared__ float f1_s[WW];
    *reinterpret_cast<float4*>(x_s + tid * 4) = *reinterpret_cast<const float4*>(x + tid * 4);
    if (tid == 0) feat[NN * WW + n] = hidden[n];
    __syncthreads();
    const float* W1n = W1 + (size_t)n * WW * DD;
    for (int r = wave * 32; r < wave * 32 + 32; ++r) {
        const float* row = W1n + (size_t)r * DD;
        float4 acc = {0.f, 0.f, 0.f, 0.f};
        #pragma unroll
        for (int it = 0; it < 4; ++it) {
            const float4 a  = *reinterpret_cast<const float4*>(row + it * 256 + lane * 4);
            const float4 xv = *reinterpret_cast<const float4*>(x_s + it * 256 + lane * 4);
            acc.x += a.x * xv.x; acc.y += a.y * xv.y;
            acc.z += a.z * xv.z; acc.w += a.w * xv.w;
        }
        float s = wred((acc.x + acc.y) + (acc.z + acc.w));
        if (lane == 0) {
            float v = s + b1[n * WW + r];
            f1_s[r] = v > 0.f ? v : 0.f;
        }
    }
    __syncthreads();
    const float* W2n = W2 + (size_t)n * WW * WW;
    for (int r = wave * 32; r < wave * 32 + 32; ++r) {
        const float2 a = *reinterpret_cast<const float2*>(W2n + (size_t)r * WW + lane * 2);
        const float2 f = *reinterpret_cast<const float2*>(f1_s + lane * 2);
        float s = wred(a.x * f.x + a.y * f.y);
        if (lane == 0) {
            float v = s + b2[n * WW + r];
            feat[n * WW + r] = v > 0.f ? v : 0.f;
        }
    }
}

__global__ __launch_bounds__(256) void sparse_kernel(
    const float* __restrict__ Wi, const float* __restrict__ mask,
    const float* __restrict__ bi, const float* __restrict__ hidden,
    const float* __restrict__ feat, float* __restrict__ out)
{
    const int n = blockIdx.x, tid = threadIdx.x;
    const float* mrow = mask + (size_t)n * FF;
    const float* wrow = Wi   + (size_t)n * FF;
    float acc = 0.f;
    for (int it = 0; it < FF / 1024; ++it) {
        const int f = it * 1024 + tid * 4;
        const float4 m = *reinterpret_cast<const float4*>(mrow + f);
        if (m.x != 0.f) acc += wrow[f + 0] * m.x * feat[f + 0];
        if (m.y != 0.f) acc += wrow[f + 1] * m.y * feat[f + 1];
        if (m.z != 0.f) acc += wrow[f + 2] * m.z * feat[f + 2];
        if (m.w != 0.f) acc += wrow[f + 3] * m.w * feat[f + 3];
    }
    acc = wred(acc);
    __shared__ float partial[4];
    if ((tid & 63) == 0) partial[tid >> 6] = acc;
    __syncthreads();
    if (tid == 0) {
        const float s = (partial[0] + partial[1]) + (partial[2] + partial[3]);
        out[1 + n] = hidden[n] + tanhf(s + bi[n]);
    }
}

extern "C" void kernel_launch(void* const* d_in, const int* in_sizes, int n_in,
                              void* d_out, int out_size, void* d_ws, size_t ws_size,
                              hipStream_t stream) {
    const float* x      = (const float*)d_in[0];
    const float* hidden = (const float*)d_in[1];
    const float* W1     = (const float*)d_in[2];
    const float* b1     = (const float*)d_in[3];
    const float* W2     = (const float*)d_in[4];
    const float* b2     = (const float*)d_in[5];
    const float* Wi     = (const float*)d_in[6];
    const float* bi     = (const float*)d_in[7];
    const float* mask   = (const float*)d_in[8];
    const float* pred   = (const float*)d_in[9];

    float* out  = (float*)d_out;
    float* feat = (float*)d_ws;
    unsigned long long* bm = (unsigned long long*)((char*)d_ws + WS_BM_OFF);

    if (ws_size >= WS_NEEDED) {
        colmlp<<<NN, 256, 0, stream>>>(x, hidden, W1, b1, W2, b2, feat);
        maskscan<<<2048, 256, 0, stream>>>(mask, bm);
        dotk<<<NN, 256, 0, stream>>>(bm, Wi, feat, bi, hidden, out);
    } else {
        feat_kernel<<<NN, 256, 0, stream>>>(x, hidden, W1, b1, W2, b2, feat);
        sparse_kernel<<<NN, 256, 0, stream>>>(Wi, mask, bi, hidden, feat, out);
    }
    predk<<<1, 256, 0, stream>>>(pred, out + 1, out);
}